// Round 6
// baseline (121.812 us; speedup 1.0000x reference)
//
#include <hip/hip_runtime.h>

// YOLO v1 loss — gatherless streaming formulation (R6).
// Shapes: output/target (8192,7,7,30) f32, grid_mask_obj (8192,7,7) i32.
//
// Phase A: grid-stride float4 streaming over BOTH tensors (m13 pattern,
//   16 B/lane, no barriers). All elementwise terms computed inline:
//     ch in [10,30): obj * (o-t)^2                (cls)
//     ch == 4 or 9 : 0.5 * (1-obj) * (o-t)^2     (noobj conf)
//     else         : 0                            (box ch -> phase B)
//   (cell,ch) tracked incrementally: stride 2,097,152 dw = 69,905 cells + 2 ch;
//   ch stays even; the only float4 cell-crossing case is ch==28.
// Phase B: one thread per cell; if obj, gather 5+5 float2 (80 B, L3-hot)
//   and compute IoU/argmax/xy/wh/conf-obj terms (verified-exact since R2).
// Reduction: wave shuffle + per-block partial store + tiny reduce kernel.

constexpr int   NCELL_  = 8192 * 7 * 7;       // 401408
constexpr int   NF4_    = NCELL_ * 30 / 4;    // 3,010,560 float4 per tensor
constexpr int   TPB_    = 256;
constexpr int   NBLK_   = 2048;               // 8 blocks/CU
constexpr int   NTH_    = TPB_ * NBLK_;       // 524288
constexpr float CELLW_  = 1.0f / 7.0f;
constexpr float IMG_    = 448.0f;
constexpr float INV_BS_ = 1.0f / 8192.0f;

__global__ __launch_bounds__(TPB_) void yolo_partial_kernel(
    const float* __restrict__ outp, const float* __restrict__ tgtp,
    const int* __restrict__ maskp, float* __restrict__ partial)
{
    const int gtid = blockIdx.x * TPB_ + threadIdx.x;
    float acc = 0.0f;

    // ---------------- Phase A: float4 streaming ----------------
    {
        const float4* o4p = reinterpret_cast<const float4*>(outp);
        const float4* t4p = reinterpret_cast<const float4*>(tgtp);

        unsigned D    = 4u * (unsigned)gtid;   // dword index of first element
        unsigned cell = D / 30u;               // compile-time magic div
        int      ch   = (int)(D - cell * 30u); // even, 0..28

        for (int i = gtid; i < NF4_; i += NTH_) {
            float4 o4 = o4p[i];
            float4 t4 = t4p[i];
            int m0 = maskp[cell];
            int m1 = maskp[(ch == 28) ? cell + 1u : cell];   // L1-hot
            float mf0 = m0 ? 1.0f : 0.0f;
            float mf1 = m1 ? 1.0f : 0.0f;

#pragma unroll
            for (int j = 0; j < 4; ++j) {
                int   chj   = ch + j;
                bool  cross = (chj >= 30);
                int   chv   = cross ? chj - 30 : chj;
                float mf    = cross ? mf1 : mf0;
                float w = (chv >= 10) ? mf
                        : ((chv == 4) | (chv == 9)) ? 0.5f * (1.0f - mf)
                        : 0.0f;
                float ov = (j == 0) ? o4.x : (j == 1) ? o4.y : (j == 2) ? o4.z : o4.w;
                float tv = (j == 0) ? t4.x : (j == 1) ? t4.y : (j == 2) ? t4.z : t4.w;
                float d = ov - tv;
                acc += w * d * d;
            }

            cell += 69905u; ch += 2;
            if (ch >= 30) { ch -= 30; cell += 1u; }
        }
    }

    // ---------------- Phase B: per-cell box terms ----------------
    if (gtid < NCELL_) {
        const int c = gtid;
        const int m = maskp[c];
        if (m) {
            const float2* po = reinterpret_cast<const float2*>(outp) + (size_t)c * 15;
            const float2* pt = reinterpret_cast<const float2*>(tgtp) + (size_t)c * 15;
            float2 a0 = po[0], a1 = po[1], a2 = po[2], a3 = po[3], a4 = po[4];
            float2 b0 = pt[0], b1 = pt[1], b2 = pt[2], b3 = pt[3], b4 = pt[4];
            // o: x0 y0 | w0 h0 | c0 x1 | y1 w1 | h1 c1  (a0..a4)
            const float o0 = a0.x, o1 = a0.y, o2 = a1.x, o3 = a1.y, o4v = a2.x;
            const float o5 = a2.y, o6 = a3.x, o7 = a3.y, o8 = a4.x, o9 = a4.y;
            const float t0 = b0.x, t1 = b0.y, t2 = b1.x, t3 = b1.y;
            const float t5 = b2.y, t6 = b3.x, t7 = b3.y, t8 = b4.x;

            const int rem = c % 49;            // row = rem/7 (y), col = rem%7 (x)
            const float gx = (float)(rem % 7) * CELLW_;
            const float gy = (float)(rem / 7) * CELLW_;

            // target box 0 -> pixel corners
            const float tx = (t0 * CELLW_ + gx) * IMG_;
            const float ty = (t1 * CELLW_ + gy) * IMG_;
            const float tw = t2 * IMG_, th = t3 * IMG_;
            const float tx1 = tx - tw * 0.5f, tx2 = tx + tw * 0.5f;
            const float ty1 = ty - th * 0.5f, ty2 = ty + th * 0.5f;
            const float area_t = (tx2 - tx1) * (ty2 - ty1);

            float iou[2];
#pragma unroll
            for (int b = 0; b < 2; ++b) {
                float bx = (b == 0) ? o0 : o5;
                float by = (b == 0) ? o1 : o6;
                float bw = (b == 0) ? o2 : o7;
                float bh = (b == 0) ? o3 : o8;
                float x = (bx * CELLW_ + gx) * IMG_;
                float y = (by * CELLW_ + gy) * IMG_;
                float w = bw * IMG_, h = bh * IMG_;
                float x1 = x - w * 0.5f, x2 = x + w * 0.5f;
                float y1 = y - h * 0.5f, y2 = y + h * 0.5f;
                float iw = fmaxf(fminf(x2, tx2) - fmaxf(x1, tx1), 0.0f);
                float ih = fmaxf(fminf(y2, ty2) - fmaxf(y1, ty1), 0.0f);
                float inter = iw * ih;
                float area_o = (x2 - x1) * (y2 - y1);
                iou[b] = inter / (area_o + area_t - inter);
            }

            const int   max_id  = (iou[1] > iou[0]) ? 1 : 0;  // argmax, tie->first
            const float max_iou = fmaxf(iou[0], iou[1]);

            const float so0 = max_id ? o5 : o0;
            const float so1 = max_id ? o6 : o1;
            const float so2 = max_id ? o7 : o2;
            const float so3 = max_id ? o8 : o3;
            const float st0 = max_id ? t5 : t0;
            const float st1 = max_id ? t6 : t1;
            const float st2 = max_id ? t7 : t2;
            const float st3 = max_id ? t8 : t3;

            const float dxy0 = so0 - st0, dxy1 = so1 - st1;
            const float xy_loss = dxy0 * dxy0 + dxy1 * dxy1;

            const float dwh0 = sqrtf(so2) - sqrtf(st2);
            const float dwh1 = sqrtf(so3) - sqrtf(st3);
            const float wh_loss = dwh0 * dwh0 + dwh1 * dwh1;

            // conf-obj: id_conf degenerates to 0 when max_iou == 0
            const int   id_conf = (max_iou > 0.0f) ? max_id : 0;
            const float sel_c   = id_conf ? o9 : o4v;
            const float sel_iou = (id_conf == max_id) ? max_iou : 0.0f;
            const float dcf     = sel_c - sel_iou;

            acc += 5.0f * (xy_loss + wh_loss) + dcf * dcf;
        }
    }

    // ---------------- reduction: wave shuffle + block partial ----------------
#pragma unroll
    for (int off = 32; off > 0; off >>= 1)
        acc += __shfl_down(acc, off);

    __shared__ float wsum[4];
    const int lane = threadIdx.x & 63;
    const int wid  = threadIdx.x >> 6;
    if (lane == 0) wsum[wid] = acc;
    __syncthreads();
    if (threadIdx.x == 0)
        partial[blockIdx.x] = wsum[0] + wsum[1] + wsum[2] + wsum[3];
}

__global__ __launch_bounds__(256) void yolo_reduce_kernel(
    const float* __restrict__ partial, float* __restrict__ out)
{
    float a = 0.0f;
    for (int i = threadIdx.x; i < NBLK_; i += 256)
        a += partial[i];

#pragma unroll
    for (int off = 32; off > 0; off >>= 1)
        a += __shfl_down(a, off);

    __shared__ float wsum[4];
    const int lane = threadIdx.x & 63;
    const int wid  = threadIdx.x >> 6;
    if (lane == 0) wsum[wid] = a;
    __syncthreads();
    if (threadIdx.x == 0)
        out[0] = (wsum[0] + wsum[1] + wsum[2] + wsum[3]) * INV_BS_;
}

extern "C" void kernel_launch(void* const* d_in, const int* in_sizes, int n_in,
                              void* d_out, int out_size, void* d_ws, size_t ws_size,
                              hipStream_t stream) {
    const float* outp = (const float*)d_in[0];
    const float* tgtp = (const float*)d_in[1];
    const int*   mask = (const int*)d_in[2];
    float*       res  = (float*)d_out;
    float*       part = (float*)d_ws;     // 2048 floats of scratch

    yolo_partial_kernel<<<NBLK_, TPB_, 0, stream>>>(outp, tgtp, mask, part);
    yolo_reduce_kernel<<<1, 256, 0, stream>>>(part, res);
}